// Round 9
// baseline (309.800 us; speedup 1.0000x reference)
//
#include <hip/hip_runtime.h>
#include <hip/hip_bf16.h>
#include <math.h>

#define SB 8     // batch
#define SS 1024  // N == M
#define SDM 512  // model dim
#define SH 8     // heads
#define SD 64    // head dim

typedef unsigned short ushort;
typedef __attribute__((ext_vector_type(8))) short bf16x8;
typedef __attribute__((ext_vector_type(4))) float f32x4;

#define MFMA16(a, b, c) __builtin_amdgcn_mfma_f32_16x16x32_bf16(a, b, c, 0, 0, 0)

static __device__ __forceinline__ ushort f2b(float f) {
    union { float f; unsigned u; } v; v.f = f;
    unsigned r = v.u + 0x7FFF + ((v.u >> 16) & 1);   // round-nearest-even
    return (ushort)(r >> 16);
}

// async global->LDS, 16 bytes per lane (dest = wave-uniform base + lane*16)
static __device__ __forceinline__ void gll16(const void* g, void* l) {
    __builtin_amdgcn_global_load_lds(
        (const __attribute__((address_space(1))) unsigned int*)g,
        (__attribute__((address_space(3))) unsigned int*)l, 16, 0, 0);
}

// ---------------------------------------------------------------------------
// Convert inputs X (q,k,v,pos) fp32 -> bf16, 8 elems/thread. grid (2048, 4).
// ---------------------------------------------------------------------------
__global__ __launch_bounds__(256) void convert_x_kernel(
    const float* __restrict__ q, const float* __restrict__ k,
    const float* __restrict__ v, const float* __restrict__ p,
    ushort* __restrict__ xbf)
{
    const int which = blockIdx.y;
    const float* src = (which == 0) ? q : (which == 1) ? k : (which == 2) ? v : p;
    ushort* dst = xbf + (size_t)which * ((size_t)SB * SS * SDM);
    size_t i = ((size_t)blockIdx.x * 256 + threadIdx.x) * 8;
    float4 a = *(const float4*)(src + i);
    float4 b = *(const float4*)(src + i + 4);
    union { ushort u[8]; uint4 v4; } o;
    o.u[0] = f2b(a.x); o.u[1] = f2b(a.y); o.u[2] = f2b(a.z); o.u[3] = f2b(a.w);
    o.u[4] = f2b(b.x); o.u[5] = f2b(b.y); o.u[6] = f2b(b.z); o.u[7] = f2b(b.w);
    *(uint4*)(dst + i) = o.v4;
}

// ---------------------------------------------------------------------------
// Convert weights -> transposed bf16 Wt[which][col][k].
// ---------------------------------------------------------------------------
__global__ __launch_bounds__(256) void convert_w_kernel(
    const float* __restrict__ qw, const float* __restrict__ kw,
    const float* __restrict__ vw, const float* __restrict__ pw,
    const float* __restrict__ projw, ushort* __restrict__ wt)
{
    const int which = blockIdx.y;
    const int idx = blockIdx.x * 256 + threadIdx.x;
    const int c  = idx >> 9;
    const int kk = idx & 511;
    float val;
    if (which < 4) {
        const float* W = (which == 0) ? qw : (which == 1) ? kw : (which == 2) ? vw : pw;
        const int h = c >> 6, d = c & 63;
        val = W[(size_t)h * SDM * SD + (size_t)kk * SD + d];
    } else {
        val = projw[(size_t)kk * SDM + c];
    }
    wt[(size_t)which * SDM * SDM + (size_t)c * SDM + kk] = f2b(val);
}

// ---------------------------------------------------------------------------
// Kernel 1: bf16 MFMA projection GEMM, 128x128 tile.
// q_u / q_v pre-scaled by 1/sqrt(D). v written chunk-tiled: [bh][mc][d][64].
// ---------------------------------------------------------------------------
__global__ __launch_bounds__(256) void projmm_kernel(
    const ushort* __restrict__ xbf, const ushort* __restrict__ wt,
    const float* __restrict__ bias_u, const float* __restrict__ bias_v,
    ushort* __restrict__ quo, ushort* __restrict__ qvo,
    ushort* __restrict__ ko, ushort* __restrict__ po,
    ushort* __restrict__ vto)
{
    __shared__ ushort Asm[128 * 32];
    __shared__ ushort Bsm[128 * 32];

    const int tid  = threadIdx.x;
    const int wave = tid >> 6, lane = tid & 63;
    const int quad = lane >> 4, l15 = lane & 15;
    const int which = blockIdx.z;
    const int row0 = blockIdx.x * 128;
    const int col0 = blockIdx.y * 128;
    const int wr = wave >> 1, wc = wave & 1;

    const ushort* A  = xbf + (size_t)which * ((size_t)SB * SS * SDM) + (size_t)row0 * SDM;
    const ushort* Bw = wt  + (size_t)which * (SDM * SDM) + (size_t)col0 * SDM;

    f32x4 acc[4][4];
#pragma unroll
    for (int i = 0; i < 4; ++i)
#pragma unroll
        for (int j = 0; j < 4; ++j) acc[i][j] = (f32x4){0.f, 0.f, 0.f, 0.f};

    for (int k0 = 0; k0 < SDM; k0 += 32) {
#pragma unroll
        for (int j = 0; j < 2; ++j) {
            int t = j * 256 + tid;
            int r = t >> 2, kp = (t & 3) * 8;
            gll16(A  + (size_t)r * SDM + k0 + kp, (char*)Asm + t * 16);
            gll16(Bw + (size_t)r * SDM + k0 + kp, (char*)Bsm + t * 16);
        }
        __syncthreads();

        bf16x8 af[4], bfr[4];
#pragma unroll
        for (int mt = 0; mt < 4; ++mt)
            af[mt] = *(const bf16x8*)&Asm[(wr * 64 + mt * 16 + l15) * 32 + quad * 8];
#pragma unroll
        for (int nt = 0; nt < 4; ++nt)
            bfr[nt] = *(const bf16x8*)&Bsm[(wc * 64 + nt * 16 + l15) * 32 + quad * 8];
#pragma unroll
        for (int mt = 0; mt < 4; ++mt)
#pragma unroll
            for (int nt = 0; nt < 4; ++nt)
                acc[mt][nt] = MFMA16(af[mt], bfr[nt], acc[mt][nt]);
        __syncthreads();
    }

    const float SC = 0.125f;   // 1/sqrt(D) folded into q
#pragma unroll
    for (int nt = 0; nt < 4; ++nt) {
        const int C = col0 + wc * 64 + nt * 16 + l15;
        const int h = C >> 6, d = C & 63;
        if (which == 0) {
            const float bu = bias_u[C];
            const float bv = bias_v[C];
#pragma unroll
            for (int mt = 0; mt < 4; ++mt) {
                const int Rb = row0 + wr * 64 + mt * 16 + quad * 4;
                const int b = Rb >> 10;
                const int n = Rb & 1023;
                const size_t base = ((size_t)(b * SH + h) * SS + n) * SD + d;
#pragma unroll
                for (int r = 0; r < 4; ++r) {
                    quo[base + (size_t)r * SD] = f2b((acc[mt][nt][r] + bu) * SC);
                    qvo[base + (size_t)r * SD] = f2b((acc[mt][nt][r] + bv) * SC);
                }
            }
        } else if (which == 1 || which == 3) {
            ushort* out = (which == 1) ? ko : po;
#pragma unroll
            for (int mt = 0; mt < 4; ++mt) {
                const int Rb = row0 + wr * 64 + mt * 16 + quad * 4;
                const int b = Rb >> 10;
                const int n = Rb & 1023;
                const size_t base = ((size_t)(b * SH + h) * SS + n) * SD + d;
#pragma unroll
                for (int r = 0; r < 4; ++r)
                    out[base + (size_t)r * SD] = f2b(acc[mt][nt][r]);
            }
        } else {
            // v chunk-tiled: vto[bh][n>>6][d][64]
#pragma unroll
            for (int mt = 0; mt < 4; ++mt) {
                const int Rb = row0 + wr * 64 + mt * 16 + quad * 4;
                const int b = Rb >> 10;
                const int n = Rb & 1023;
                union { ushort u[4]; uint2 v2; } pk;
#pragma unroll
                for (int r = 0; r < 4; ++r) pk.u[r] = f2b(acc[mt][nt][r]);
                const size_t base = (size_t)(b * SH + h) * SS * SD
                                  + ((size_t)((n >> 6) * 64 + d)) * 64 + (n & 63);
                *(uint2*)&vto[base] = pk.v2;
            }
        }
    }
}

// XOR-swizzled LDS fragment read: 16B segment `seg` of logical row `row`
// (row stride 64 ushorts = 128 B; store placed seg at slot seg^(row&7)).
static __device__ __forceinline__ bf16x8 sfrag(const ushort* buf, int row, int seg) {
    return *(const bf16x8*)&buf[(size_t)row * 64 + ((seg ^ (row & 7)) * 8)];
}

// ---------------------------------------------------------------------------
// Kernel 2: bf16 MFMA attention — round-0 skeleton, OCCUPANCY unlock.
// Evidence (r0..r8): Glds-gather skeleton is fastest (102 us); bank
// conflicts (5.4 M, stride-invariant) are NON-BINDING (~21 kcyc/CU of a
// 245 kcyc kernel; stride 83 changed nothing). The binding constraint is
// occupancy: every Glds variant ran 3 blocks/CU (LDS-bound), ~20% occ,
// latency-bound (Mfma 11 / VALU 39 / HBM 3.6%).
// This round: drop Kb (-8 KB) -> k fragments read DIRECT from global (L2,
// same 16-row x 16B pattern v uses), issued right after the barrier and
// consumed only after the band GEMM + Glds writes (~300 cyc of Pb-only
// work hides the ~200 cyc L2 latency). Glds(stride 80)/Plds union kept.
// LDS = Pb 16 KB + 4x5 KB union = 36 864 B -> 4 blocks/CU (16 waves/CU).
// Staging DMA per barrier drops 6 -> 4 gll16 (shorter vmcnt drain).
// Do not revisit: bpermute gathers (r2/6/7 lose at iso-occupancy),
// zero-staging (r3, 2.5x loss), forced launch_bounds (r1, spills).
// XCD-clustered grid (1024): all 16 n-tiles of a (b,h) share an XCD L2.
// ---------------------------------------------------------------------------
__global__ __launch_bounds__(256) void attn_kernel(
    const ushort* __restrict__ qu, const ushort* __restrict__ qv,
    const ushort* __restrict__ kk, const ushort* __restrict__ pp,
    const ushort* __restrict__ vt, ushort* __restrict__ ctx)
{
    union GPshare {
        float  g[16][80];   // 5120 B gather scratch
        ushort p[16][72];   // 2304 B P C->A transform
    };
    __shared__ ushort  Pb[128 * 64];     // 16 KB staged p band
    __shared__ GPshare GP[4];            // 20 KB wave-private (union)

    const int tid  = threadIdx.x;
    const int wave = tid >> 6;
    const int lane = tid & 63;
    const int quad = lane >> 4;
    const int l15  = lane & 15;

    const int id   = blockIdx.x;
    const int xcd  = id & 7;
    const int slot = id >> 3;               // 0..127
    const int bhid = xcd * 8 + (slot >> 4); // 0..63
    const int nt   = slot & 15;
    const int b    = bhid >> 3;
    const int h    = bhid & 7;
    const int n0   = nt * 64;

    const size_t bh   = (size_t)(b * SH + h);
    const ushort* qu_bh = qu + bh * SS * SD;
    const ushort* qv_bh = qv + bh * SS * SD;
    const ushort* k_bh  = kk + bh * SS * SD;
    const ushort* p_bh  = pp + bh * SS * SD;
    const ushort* vt_bh = vt + bh * SS * SD;   // chunk-tiled [mc][d][64]

    const int mcD = n0 >> 6;   // diagonal chunk index

    const int arow  = n0 + wave * 16 + l15;
    const int arow2 = (arow + 1 < SS) ? arow + 1 : SS - 1;

    bf16x8 a_u0  = *(const bf16x8*)(qu_bh + (size_t)arow  * SD + quad * 8);
    bf16x8 a_u1  = *(const bf16x8*)(qu_bh + (size_t)arow  * SD + quad * 8 + 32);
    bf16x8 a_vl0 = *(const bf16x8*)(qv_bh + (size_t)arow  * SD + quad * 8);
    bf16x8 a_vl1 = *(const bf16x8*)(qv_bh + (size_t)arow  * SD + quad * 8 + 32);
    bf16x8 a_vu0 = *(const bf16x8*)(qv_bh + (size_t)arow2 * SD + quad * 8);
    bf16x8 a_vu1 = *(const bf16x8*)(qv_bh + (size_t)arow2 * SD + quad * 8 + 32);

    float lsum[4] = {0.f, 0.f, 0.f, 0.f};
    f32x4 O[4];
#pragma unroll
    for (int dt = 0; dt < 4; ++dt) O[dt] = (f32x4){0.f, 0.f, 0.f, 0.f};

    float  (*Gl)[80] = GP[wave].g;
    ushort (*Pl)[72] = GP[wave].p;

    // stage chunk mc's p band (128 rows) into LDS, XOR-swizzled
    auto stage = [&](int mc) {
        const int m0s = mc * 64;
        const int cb  = (mc <= mcD) ? (m0s - n0 + 960) : (m0s - n0 - 65);
#pragma unroll
        for (int it = 0; it < 4; ++it) {
            int t = it * 256 + tid;
            int r = t >> 3, s = t & 7;
            int c = cb + r; c = (c < 0) ? 0 : (c > SS - 1 ? SS - 1 : c);
            gll16(p_bh + (size_t)c * 64 + ((s ^ (r & 7)) * 8),
                  (char*)Pb + t * 16);
        }
    };

    stage(0);

    for (int mc = 0; mc < 16; ++mc) {
        const int m0 = mc * 64;
        const int diff = m0 - n0;
        const bool lowerband = (mc <= mcD);

        __syncthreads();   // staged Pb ready (compiler drains vmcnt before barrier)

        // ---- issue k fragment loads (direct global, L2); consumed after
        //      the band GEMM below so their latency hides under Pb work ----
        bf16x8 kf0[4], kf1[4];
#pragma unroll
        for (int mt = 0; mt < 4; ++mt) {
            const ushort* kr = k_bh + (size_t)(m0 + mt * 16 + l15) * SD + quad * 8;
            kf0[mt] = *(const bf16x8*)kr;
            kf1[mt] = *(const bf16x8*)(kr + 32);
        }

        // ---- band GEMM from staged Pb -> Glds writes ----
        {
            const bf16x8 av0 = lowerband ? a_vl0 : a_vu0;
            const bf16x8 av1 = lowerband ? a_vl1 : a_vu1;
#pragma unroll
            for (int ti = 0; ti < 5; ++ti) {
                const int t = (3 - wave + ti) * 16 + l15;
                f32x4 g = (f32x4){0.f, 0.f, 0.f, 0.f};
                g = MFMA16(av0, sfrag(Pb, t, quad), g);
                g = MFMA16(av1, sfrag(Pb, t, quad + 4), g);
#pragma unroll
                for (int r = 0; r < 4; ++r)
                    Gl[quad * 4 + r][ti * 16 + l15] = g[r];
            }
        }

        // ---- S_u = q_u . k^T (k fragments have arrived by now) ----
        f32x4 S[4];
#pragma unroll
        for (int mt = 0; mt < 4; ++mt) {
            f32x4 c = (f32x4){0.f, 0.f, 0.f, 0.f};
            c = MFMA16(a_u0, kf0[mt], c);
            c = MFMA16(a_u1, kf1[mt], c);
            S[mt] = c;
        }

        // ---- diagonal gather from Glds ----
        float sv[4][4];
#pragma unroll
        for (int mt = 0; mt < 4; ++mt) {
            const int mloc = mt * 16 + l15;
#pragma unroll
            for (int r = 0; r < 4; ++r) {
                const int q4r = quad * 4 + r;
                const int d1 = diff + mloc - (wave * 16 + q4r);
                const bool use = lowerband ? (d1 <= 0) : (d1 >= 2);
                sv[mt][r] = use ? Gl[q4r][mloc - q4r + 15] : 0.f;
            }
        }

        // ---- diagonal chunk: upper band direct from global ----
        if (mc == mcD) {
            const int cbase = diff - 65;
            bf16x8 pu0[5], pu1[5];
#pragma unroll
            for (int ti = 0; ti < 5; ++ti) {
                int t = (3 - wave + ti) * 16 + l15;
                int c = cbase + t;
                c = (c < 0) ? 0 : (c > SS - 1 ? SS - 1 : c);
                const ushort* pr = p_bh + (size_t)c * SD + quad * 8;
                pu0[ti] = *(const bf16x8*)pr;
                pu1[ti] = *(const bf16x8*)(pr + 32);
            }
#pragma unroll
            for (int ti = 0; ti < 5; ++ti) {
                f32x4 g = (f32x4){0.f, 0.f, 0.f, 0.f};
                g = MFMA16(a_vu0, pu0[ti], g);
                g = MFMA16(a_vu1, pu1[ti], g);
#pragma unroll
                for (int r = 0; r < 4; ++r)
                    Gl[quad * 4 + r][ti * 16 + l15] = g[r];
            }
#pragma unroll
            for (int mt = 0; mt < 4; ++mt) {
                const int mloc = mt * 16 + l15;
#pragma unroll
                for (int r = 0; r < 4; ++r) {
                    const int q4r = quad * 4 + r;
                    const int d1 = diff + mloc - (wave * 16 + q4r);
                    if (d1 >= 2) sv[mt][r] = Gl[q4r][mloc - q4r + 15];
                }
            }
        }

        __syncthreads();   // all waves done reading Pb
        if (mc + 1 < 16) stage(mc + 1);   // DMA overlaps exp/PV below

        // ---- v burst (direct, line-aligned chunk-tiled rows) ----
        bf16x8 vb0[4], vb1[4];
#pragma unroll
        for (int dt = 0; dt < 4; ++dt) {
            const ushort* vp = vt_bh + (size_t)(m0 + dt * 16 + l15) * 64 + quad * 8;
            vb0[dt] = *(const bf16x8*)vp;
            vb1[dt] = *(const bf16x8*)(vp + 32);
        }

        // ---- e = exp(logit), lane-local l accumulation ----
        float e[4][4];
#pragma unroll
        for (int mt = 0; mt < 4; ++mt)
#pragma unroll
            for (int r = 0; r < 4; ++r) {
                e[mt][r] = __expf(S[mt][r] + sv[mt][r]);
                lsum[r] += e[mt][r];
            }

        // ---- P: C-layout -> A-layout via LDS (aliases Glds; gather reads
        //      above completed in-order before these writes) ----
#pragma unroll
        for (int mt = 0; mt < 4; ++mt)
#pragma unroll
            for (int r = 0; r < 4; ++r)
                Pl[quad * 4 + r][mt * 16 + l15] = f2b(e[mt][r]);

        // ---- O += P . V ----
        bf16x8 ap0 = *(const bf16x8*)&Pl[l15][quad * 8];
        bf16x8 ap1 = *(const bf16x8*)&Pl[l15][32 + quad * 8];
#pragma unroll
        for (int dt = 0; dt < 4; ++dt) {
            O[dt] = MFMA16(ap0, vb0[dt], O[dt]);
            O[dt] = MFMA16(ap1, vb1[dt], O[dt]);
        }
    }

    // final l reduction across the 16 lanes of each row group
#pragma unroll
    for (int mask = 1; mask <= 8; mask <<= 1)
#pragma unroll
        for (int r = 0; r < 4; ++r)
            lsum[r] += __shfl_xor(lsum[r], mask, 16);

    float inv[4];
#pragma unroll
    for (int r = 0; r < 4; ++r) inv[r] = 1.f / lsum[r];

#pragma unroll
    for (int dt = 0; dt < 4; ++dt)
#pragma unroll
        for (int r = 0; r < 4; ++r) {
            int nn = n0 + wave * 16 + quad * 4 + r;
            ctx[((size_t)b * SS + nn) * (SH * SD) + h * SD + dt * 16 + l15] =
                f2b(O[dt][r] * inv[r]);
        }
}

// ---------------------------------------------------------------------------
// Kernel 3: output projection, bf16 MFMA GEMM.
// ---------------------------------------------------------------------------
__global__ __launch_bounds__(256) void outproj_kernel(
    const ushort* __restrict__ ctx, const ushort* __restrict__ wt,
    float* __restrict__ out)
{
    __shared__ ushort Asm[128 * 32];
    __shared__ ushort Bsm[128 * 32];

    const int tid  = threadIdx.x;
    const int wave = tid >> 6, lane = tid & 63;
    const int quad = lane >> 4, l15 = lane & 15;
    const int row0 = blockIdx.x * 128;
    const int col0 = blockIdx.y * 128;
    const int wr = wave >> 1, wc = wave & 1;

    const ushort* A  = ctx + (size_t)row0 * SDM;
    const ushort* Bw = wt + (size_t)4 * (SDM * SDM) + (size_t)col0 * SDM;

    f32x4 acc[4][4];
#pragma unroll
    for (int i = 0; i < 4; ++i)
#pragma unroll
        for (int j = 0; j < 4; ++j) acc[i][j] = (f32x4){0.f, 0.f, 0.f, 0.f};

    for (int k0 = 0; k0 < SDM; k0 += 32) {
#pragma unroll
        for (int j = 0; j < 2; ++j) {
            int t = j * 256 + tid;
            int r = t >> 2, kp = (t & 3) * 8;
            gll16(A  + (size_t)r * SDM + k0 + kp, (char*)Asm + t * 16);
            gll16(Bw + (size_t)r * SDM + k0 + kp, (char*)Bsm + t * 16);
        }
        __syncthreads();

        bf16x8 af[4], bfr[4];
#pragma unroll
        for (int mt = 0; mt < 4; ++mt)
            af[mt] = *(const bf16x8*)&Asm[(wr * 64 + mt * 16 + l15) * 32 + quad * 8];
#pragma unroll
        for (int nt = 0; nt < 4; ++nt)
            bfr[nt] = *(const bf16x8*)&Bsm[(wc * 64 + nt * 16 + l15) * 32 + quad * 8];
#pragma unroll
        for (int mt = 0; mt < 4; ++mt)
#pragma unroll
            for (int nt = 0; nt < 4; ++nt)
                acc[mt][nt] = MFMA16(af[mt], bfr[nt], acc[mt][nt]);
        __syncthreads();
    }

#pragma unroll
    for (int mt = 0; mt < 4; ++mt)
#pragma unroll
        for (int nt = 0; nt < 4; ++nt) {
            const int R = row0 + wr * 64 + mt * 16 + quad * 4;
            const int C = col0 + wc * 64 + nt * 16 + l15;
#pragma unroll
            for (int r = 0; r < 4; ++r)
                out[(size_t)(R + r) * SDM + C] = acc[mt][nt][r];
        }
}

// ---------------------------------------------------------------------------
extern "C" void kernel_launch(void* const* d_in, const int* in_sizes, int n_in,
                              void* d_out, int out_size, void* d_ws, size_t ws_size,
                              hipStream_t stream)
{
    const float* query  = (const float*)d_in[0];
    const float* key    = (const float*)d_in[1];
    const float* value  = (const float*)d_in[2];
    const float* pos    = (const float*)d_in[3];
    const float* qw     = (const float*)d_in[4];
    const float* kw     = (const float*)d_in[5];
    const float* vw     = (const float*)d_in[6];
    const float* pw     = (const float*)d_in[7];
    const float* projw  = (const float*)d_in[8];
    const float* bias_u = (const float*)d_in[9];
    const float* bias_v = (const float*)d_in[10];

    char* w = (char*)d_ws;
    const size_t MB = 1024 * 1024;
    ushort* xbf = (ushort*)w;                 // 32 MB (dead after projmm)
    ushort* quo = (ushort*)(w + 32 * MB);
    ushort* qvo = (ushort*)(w + 40 * MB);
    ushort* ko  = (ushort*)(w + 48 * MB);
    ushort* po  = (ushort*)(w + 56 * MB);
    ushort* vto = (ushort*)(w + 64 * MB);     // chunk-tiled [bh][mc][d][64]
    ushort* wt  = (ushort*)(w + 72 * MB);     // 2.5 MB
    ushort* ctx = (ushort*)w;                 // aliases dead xbf

    dim3 gcx(2048, 4);
    convert_x_kernel<<<gcx, 256, 0, stream>>>(query, key, value, pos, xbf);
    dim3 gcw(1024, 5);
    convert_w_kernel<<<gcw, 256, 0, stream>>>(qw, kw, vw, pw, projw, wt);

    dim3 g1(64, 4, 4);
    projmm_kernel<<<g1, 256, 0, stream>>>(xbf, wt, bias_u, bias_v,
                                          quo, qvo, ko, po, vto);

    attn_kernel<<<dim3(1024), 256, 0, stream>>>(quo, qvo, ko, po, vto, ctx);

    dim3 g3(64, 4);
    outproj_kernel<<<g3, 256, 0, stream>>>(ctx, wt, (float*)d_out);
}

// Round 10
// 276.804 us; speedup vs baseline: 1.1192x; 1.1192x over previous
//
#include <hip/hip_runtime.h>
#include <hip/hip_bf16.h>
#include <math.h>

#define SB 8     // batch
#define SS 1024  // N == M
#define SDM 512  // model dim
#define SH 8     // heads
#define SD 64    // head dim

typedef unsigned short ushort;
typedef __attribute__((ext_vector_type(8))) short bf16x8;
typedef __attribute__((ext_vector_type(4))) float f32x4;

#define MFMA16(a, b, c) __builtin_amdgcn_mfma_f32_16x16x32_bf16(a, b, c, 0, 0, 0)

static __device__ __forceinline__ ushort f2b(float f) {
    union { float f; unsigned u; } v; v.f = f;
    unsigned r = v.u + 0x7FFF + ((v.u >> 16) & 1);   // round-nearest-even
    return (ushort)(r >> 16);
}

// async global->LDS, 16 bytes per lane (dest = wave-uniform base + lane*16)
static __device__ __forceinline__ void gll16(const void* g, void* l) {
    __builtin_amdgcn_global_load_lds(
        (const __attribute__((address_space(1))) unsigned int*)g,
        (__attribute__((address_space(3))) unsigned int*)l, 16, 0, 0);
}

// ---------------------------------------------------------------------------
// Convert inputs X (q,k,v,pos) fp32 -> bf16, 8 elems/thread. grid (2048, 4).
// ---------------------------------------------------------------------------
__global__ __launch_bounds__(256) void convert_x_kernel(
    const float* __restrict__ q, const float* __restrict__ k,
    const float* __restrict__ v, const float* __restrict__ p,
    ushort* __restrict__ xbf)
{
    const int which = blockIdx.y;
    const float* src = (which == 0) ? q : (which == 1) ? k : (which == 2) ? v : p;
    ushort* dst = xbf + (size_t)which * ((size_t)SB * SS * SDM);
    size_t i = ((size_t)blockIdx.x * 256 + threadIdx.x) * 8;
    float4 a = *(const float4*)(src + i);
    float4 b = *(const float4*)(src + i + 4);
    union { ushort u[8]; uint4 v4; } o;
    o.u[0] = f2b(a.x); o.u[1] = f2b(a.y); o.u[2] = f2b(a.z); o.u[3] = f2b(a.w);
    o.u[4] = f2b(b.x); o.u[5] = f2b(b.y); o.u[6] = f2b(b.z); o.u[7] = f2b(b.w);
    *(uint4*)(dst + i) = o.v4;
}

// ---------------------------------------------------------------------------
// Convert weights -> transposed bf16 Wt[which][col][k].
// ---------------------------------------------------------------------------
__global__ __launch_bounds__(256) void convert_w_kernel(
    const float* __restrict__ qw, const float* __restrict__ kw,
    const float* __restrict__ vw, const float* __restrict__ pw,
    const float* __restrict__ projw, ushort* __restrict__ wt)
{
    const int which = blockIdx.y;
    const int idx = blockIdx.x * 256 + threadIdx.x;
    const int c  = idx >> 9;
    const int kk = idx & 511;
    float val;
    if (which < 4) {
        const float* W = (which == 0) ? qw : (which == 1) ? kw : (which == 2) ? vw : pw;
        const int h = c >> 6, d = c & 63;
        val = W[(size_t)h * SDM * SD + (size_t)kk * SD + d];
    } else {
        val = projw[(size_t)kk * SDM + c];
    }
    wt[(size_t)which * SDM * SDM + (size_t)c * SDM + kk] = f2b(val);
}

// ---------------------------------------------------------------------------
// Kernel 1: bf16 MFMA projection GEMM, 128x128 tile, BK=64 (halved barrier
// count vs BK=32; kk-inner fragment reads keep VGPR flat). LDS 32 KB.
// q_u / q_v pre-scaled by 1/sqrt(D). v written chunk-tiled: [bh][mc][d][64].
// ---------------------------------------------------------------------------
__global__ __launch_bounds__(256) void projmm_kernel(
    const ushort* __restrict__ xbf, const ushort* __restrict__ wt,
    const float* __restrict__ bias_u, const float* __restrict__ bias_v,
    ushort* __restrict__ quo, ushort* __restrict__ qvo,
    ushort* __restrict__ ko, ushort* __restrict__ po,
    ushort* __restrict__ vto)
{
    __shared__ ushort Asm[128 * 64];
    __shared__ ushort Bsm[128 * 64];

    const int tid  = threadIdx.x;
    const int wave = tid >> 6, lane = tid & 63;
    const int quad = lane >> 4, l15 = lane & 15;
    const int which = blockIdx.z;
    const int row0 = blockIdx.x * 128;
    const int col0 = blockIdx.y * 128;
    const int wr = wave >> 1, wc = wave & 1;

    const ushort* A  = xbf + (size_t)which * ((size_t)SB * SS * SDM) + (size_t)row0 * SDM;
    const ushort* Bw = wt  + (size_t)which * (SDM * SDM) + (size_t)col0 * SDM;

    f32x4 acc[4][4];
#pragma unroll
    for (int i = 0; i < 4; ++i)
#pragma unroll
        for (int j = 0; j < 4; ++j) acc[i][j] = (f32x4){0.f, 0.f, 0.f, 0.f};

    for (int k0 = 0; k0 < SDM; k0 += 64) {
#pragma unroll
        for (int j = 0; j < 4; ++j) {
            int t = j * 256 + tid;
            int r = t >> 3, kp = (t & 7) * 8;
            gll16(A  + (size_t)r * SDM + k0 + kp, (char*)Asm + t * 16);
            gll16(Bw + (size_t)r * SDM + k0 + kp, (char*)Bsm + t * 16);
        }
        __syncthreads();

#pragma unroll
        for (int kk = 0; kk < 2; ++kk) {
            bf16x8 af[4], bfr[4];
#pragma unroll
            for (int mt = 0; mt < 4; ++mt)
                af[mt] = *(const bf16x8*)&Asm[(wr * 64 + mt * 16 + l15) * 64 + kk * 32 + quad * 8];
#pragma unroll
            for (int nt = 0; nt < 4; ++nt)
                bfr[nt] = *(const bf16x8*)&Bsm[(wc * 64 + nt * 16 + l15) * 64 + kk * 32 + quad * 8];
#pragma unroll
            for (int mt = 0; mt < 4; ++mt)
#pragma unroll
                for (int nt = 0; nt < 4; ++nt)
                    acc[mt][nt] = MFMA16(af[mt], bfr[nt], acc[mt][nt]);
        }
        __syncthreads();
    }

    const float SC = 0.125f;   // 1/sqrt(D) folded into q
#pragma unroll
    for (int nt = 0; nt < 4; ++nt) {
        const int C = col0 + wc * 64 + nt * 16 + l15;
        const int h = C >> 6, d = C & 63;
        if (which == 0) {
            const float bu = bias_u[C];
            const float bv = bias_v[C];
#pragma unroll
            for (int mt = 0; mt < 4; ++mt) {
                const int Rb = row0 + wr * 64 + mt * 16 + quad * 4;
                const int b = Rb >> 10;
                const int n = Rb & 1023;
                const size_t base = ((size_t)(b * SH + h) * SS + n) * SD + d;
#pragma unroll
                for (int r = 0; r < 4; ++r) {
                    quo[base + (size_t)r * SD] = f2b((acc[mt][nt][r] + bu) * SC);
                    qvo[base + (size_t)r * SD] = f2b((acc[mt][nt][r] + bv) * SC);
                }
            }
        } else if (which == 1 || which == 3) {
            ushort* out = (which == 1) ? ko : po;
#pragma unroll
            for (int mt = 0; mt < 4; ++mt) {
                const int Rb = row0 + wr * 64 + mt * 16 + quad * 4;
                const int b = Rb >> 10;
                const int n = Rb & 1023;
                const size_t base = ((size_t)(b * SH + h) * SS + n) * SD + d;
#pragma unroll
                for (int r = 0; r < 4; ++r)
                    out[base + (size_t)r * SD] = f2b(acc[mt][nt][r]);
            }
        } else {
            // v chunk-tiled: vto[bh][n>>6][d][64]
#pragma unroll
            for (int mt = 0; mt < 4; ++mt) {
                const int Rb = row0 + wr * 64 + mt * 16 + quad * 4;
                const int b = Rb >> 10;
                const int n = Rb & 1023;
                union { ushort u[4]; uint2 v2; } pk;
#pragma unroll
                for (int r = 0; r < 4; ++r) pk.u[r] = f2b(acc[mt][nt][r]);
                const size_t base = (size_t)(b * SH + h) * SS * SD
                                  + ((size_t)((n >> 6) * 64 + d)) * 64 + (n & 63);
                *(uint2*)&vto[base] = pk.v2;
            }
        }
    }
}

// XOR-swizzled LDS fragment read: 16B segment `seg` of logical row `row`
// (row stride 64 ushorts = 128 B; store placed seg at slot seg^(row&7)).
static __device__ __forceinline__ bf16x8 sfrag(const ushort* buf, int row, int seg) {
    return *(const bf16x8*)&buf[(size_t)row * 64 + ((seg ^ (row & 7)) * 8)];
}

// ---------------------------------------------------------------------------
// Kernel 2: bf16 MFMA attention — r8 skeleton (verified 102 us) with ONE
// scheduling change: barrier2 + stage(mc+1) moved up to right after the
// band GEMM (the LAST Kb/Pb reader; the diagonal section reads p direct
// from global and Glds is wave-private). The staging DMA now overlaps the
// gather + diagonal + v-burst + exp + P-transform + PV (~3x more cover),
// shrinking the vmcnt-drain stall at the next chunk's barrier1.
// Cost model (r0-r9): kernel is DS-pipe + barrier-serialization bound;
// conflicts (5.4 M) non-binding; occupancy non-binding (r9: 4 blocks/CU
// at 148 us); staged DMA beats direct loads for k/p (r3: 2.5x, r9: 1.45x).
// Do not revisit: bpermute gathers (r2/6/7 — shuffles are DS ops too),
// zero-staging (r3), k-direct (r9), forced launch_bounds (r1, spills).
// XCD-clustered grid (1024): all 16 n-tiles of a (b,h) share an XCD L2.
// ---------------------------------------------------------------------------
__global__ __launch_bounds__(256) void attn_kernel(
    const ushort* __restrict__ qu, const ushort* __restrict__ qv,
    const ushort* __restrict__ kk, const ushort* __restrict__ pp,
    const ushort* __restrict__ vt, ushort* __restrict__ ctx)
{
    union GPshare {
        float  g[16][80];   // 5120 B gather scratch
        ushort p[16][72];   // 2304 B P C->A transform
    };
    __shared__ ushort  Kb[64 * 64];      //  8 KB staged k chunk
    __shared__ ushort  Pb[128 * 64];     // 16 KB staged p band
    __shared__ GPshare GP[4];            // 20 KB wave-private (union)

    const int tid  = threadIdx.x;
    const int wave = tid >> 6;
    const int lane = tid & 63;
    const int quad = lane >> 4;
    const int l15  = lane & 15;

    const int id   = blockIdx.x;
    const int xcd  = id & 7;
    const int slot = id >> 3;               // 0..127
    const int bhid = xcd * 8 + (slot >> 4); // 0..63
    const int nt   = slot & 15;
    const int b    = bhid >> 3;
    const int h    = bhid & 7;
    const int n0   = nt * 64;

    const size_t bh   = (size_t)(b * SH + h);
    const ushort* qu_bh = qu + bh * SS * SD;
    const ushort* qv_bh = qv + bh * SS * SD;
    const ushort* k_bh  = kk + bh * SS * SD;
    const ushort* p_bh  = pp + bh * SS * SD;
    const ushort* vt_bh = vt + bh * SS * SD;   // chunk-tiled [mc][d][64]

    const int mcD = n0 >> 6;   // diagonal chunk index

    const int arow  = n0 + wave * 16 + l15;
    const int arow2 = (arow + 1 < SS) ? arow + 1 : SS - 1;

    bf16x8 a_u0  = *(const bf16x8*)(qu_bh + (size_t)arow  * SD + quad * 8);
    bf16x8 a_u1  = *(const bf16x8*)(qu_bh + (size_t)arow  * SD + quad * 8 + 32);
    bf16x8 a_vl0 = *(const bf16x8*)(qv_bh + (size_t)arow  * SD + quad * 8);
    bf16x8 a_vl1 = *(const bf16x8*)(qv_bh + (size_t)arow  * SD + quad * 8 + 32);
    bf16x8 a_vu0 = *(const bf16x8*)(qv_bh + (size_t)arow2 * SD + quad * 8);
    bf16x8 a_vu1 = *(const bf16x8*)(qv_bh + (size_t)arow2 * SD + quad * 8 + 32);

    float lsum[4] = {0.f, 0.f, 0.f, 0.f};
    f32x4 O[4];
#pragma unroll
    for (int dt = 0; dt < 4; ++dt) O[dt] = (f32x4){0.f, 0.f, 0.f, 0.f};

    float  (*Gl)[80] = GP[wave].g;
    ushort (*Pl)[72] = GP[wave].p;

    // stage chunk mc's k (64 rows) + p band (128 rows) into LDS, XOR-swizzled
    auto stage = [&](int mc) {
        const int m0s = mc * 64;
        const int cb  = (mc <= mcD) ? (m0s - n0 + 960) : (m0s - n0 - 65);
#pragma unroll
        for (int it = 0; it < 2; ++it) {
            int t = it * 256 + tid;
            int r = t >> 3, s = t & 7;
            gll16(k_bh + (size_t)(m0s + r) * 64 + ((s ^ (r & 7)) * 8),
                  (char*)Kb + t * 16);
        }
#pragma unroll
        for (int it = 0; it < 4; ++it) {
            int t = it * 256 + tid;
            int r = t >> 3, s = t & 7;
            int c = cb + r; c = (c < 0) ? 0 : (c > SS - 1 ? SS - 1 : c);
            gll16(p_bh + (size_t)c * 64 + ((s ^ (r & 7)) * 8),
                  (char*)Pb + t * 16);
        }
    };

    stage(0);

    for (int mc = 0; mc < 16; ++mc) {
        const int m0 = mc * 64;
        const int diff = m0 - n0;
        const bool lowerband = (mc <= mcD);

        __syncthreads();   // staged data ready (compiler drains vmcnt before barrier)

        // ---- S_u = q_u . k^T from staged Kb ----
        f32x4 S[4];
#pragma unroll
        for (int mt = 0; mt < 4; ++mt) {
            const int r = mt * 16 + l15;
            f32x4 c = (f32x4){0.f, 0.f, 0.f, 0.f};
            c = MFMA16(a_u0, sfrag(Kb, r, quad), c);
            c = MFMA16(a_u1, sfrag(Kb, r, quad + 4), c);
            S[mt] = c;
        }

        // ---- staged band GEMM -> Glds writes (LAST Kb/Pb reader) ----
        {
            const bf16x8 av0 = lowerband ? a_vl0 : a_vu0;
            const bf16x8 av1 = lowerband ? a_vl1 : a_vu1;
#pragma unroll
            for (int ti = 0; ti < 5; ++ti) {
                const int t = (3 - wave + ti) * 16 + l15;
                f32x4 g = (f32x4){0.f, 0.f, 0.f, 0.f};
                g = MFMA16(av0, sfrag(Pb, t, quad), g);
                g = MFMA16(av1, sfrag(Pb, t, quad + 4), g);
#pragma unroll
                for (int r = 0; r < 4; ++r)
                    Gl[quad * 4 + r][ti * 16 + l15] = g[r];
            }
        }

        __syncthreads();   // all waves done reading Kb/Pb (nothing below reads them)
        if (mc + 1 < 16) stage(mc + 1);   // DMA overlaps gather/diag/v/exp/PV

        // ---- diagonal gather from Glds (wave-private, no sync needed) ----
        float sv[4][4];
#pragma unroll
        for (int mt = 0; mt < 4; ++mt) {
            const int mloc = mt * 16 + l15;
#pragma unroll
            for (int r = 0; r < 4; ++r) {
                const int q4r = quad * 4 + r;
                const int d1 = diff + mloc - (wave * 16 + q4r);
                const bool use = lowerband ? (d1 <= 0) : (d1 >= 2);
                sv[mt][r] = use ? Gl[q4r][mloc - q4r + 15] : 0.f;
            }
        }

        // ---- diagonal chunk: upper band direct from global ----
        if (mc == mcD) {
            const int cbase = diff - 65;
            bf16x8 pu0[5], pu1[5];
#pragma unroll
            for (int ti = 0; ti < 5; ++ti) {
                int t = (3 - wave + ti) * 16 + l15;
                int c = cbase + t;
                c = (c < 0) ? 0 : (c > SS - 1 ? SS - 1 : c);
                const ushort* pr = p_bh + (size_t)c * SD + quad * 8;
                pu0[ti] = *(const bf16x8*)pr;
                pu1[ti] = *(const bf16x8*)(pr + 32);
            }
#pragma unroll
            for (int ti = 0; ti < 5; ++ti) {
                f32x4 g = (f32x4){0.f, 0.f, 0.f, 0.f};
                g = MFMA16(a_vu0, pu0[ti], g);
                g = MFMA16(a_vu1, pu1[ti], g);
#pragma unroll
                for (int r = 0; r < 4; ++r)
                    Gl[quad * 4 + r][ti * 16 + l15] = g[r];
            }
#pragma unroll
            for (int mt = 0; mt < 4; ++mt) {
                const int mloc = mt * 16 + l15;
#pragma unroll
                for (int r = 0; r < 4; ++r) {
                    const int q4r = quad * 4 + r;
                    const int d1 = diff + mloc - (wave * 16 + q4r);
                    if (d1 >= 2) sv[mt][r] = Gl[q4r][mloc - q4r + 15];
                }
            }
        }

        // ---- v burst (direct, line-aligned chunk-tiled rows) ----
        bf16x8 vb0[4], vb1[4];
#pragma unroll
        for (int dt = 0; dt < 4; ++dt) {
            const ushort* vp = vt_bh + (size_t)(m0 + dt * 16 + l15) * 64 + quad * 8;
            vb0[dt] = *(const bf16x8*)vp;
            vb1[dt] = *(const bf16x8*)(vp + 32);
        }

        // ---- e = exp(logit), lane-local l accumulation ----
        float e[4][4];
#pragma unroll
        for (int mt = 0; mt < 4; ++mt)
#pragma unroll
            for (int r = 0; r < 4; ++r) {
                e[mt][r] = __expf(S[mt][r] + sv[mt][r]);
                lsum[r] += e[mt][r];
            }

        // ---- P: C-layout -> A-layout via LDS (aliases Glds; gather reads
        //      above completed in-order before these writes) ----
#pragma unroll
        for (int mt = 0; mt < 4; ++mt)
#pragma unroll
            for (int r = 0; r < 4; ++r)
                Pl[quad * 4 + r][mt * 16 + l15] = f2b(e[mt][r]);

        // ---- O += P . V ----
        bf16x8 ap0 = *(const bf16x8*)&Pl[l15][quad * 8];
        bf16x8 ap1 = *(const bf16x8*)&Pl[l15][32 + quad * 8];
#pragma unroll
        for (int dt = 0; dt < 4; ++dt) {
            O[dt] = MFMA16(ap0, vb0[dt], O[dt]);
            O[dt] = MFMA16(ap1, vb1[dt], O[dt]);
        }
    }

    // final l reduction across the 16 lanes of each row group
#pragma unroll
    for (int mask = 1; mask <= 8; mask <<= 1)
#pragma unroll
        for (int r = 0; r < 4; ++r)
            lsum[r] += __shfl_xor(lsum[r], mask, 16);

    float inv[4];
#pragma unroll
    for (int r = 0; r < 4; ++r) inv[r] = 1.f / lsum[r];

#pragma unroll
    for (int dt = 0; dt < 4; ++dt)
#pragma unroll
        for (int r = 0; r < 4; ++r) {
            int nn = n0 + wave * 16 + quad * 4 + r;
            ctx[((size_t)b * SS + nn) * (SH * SD) + h * SD + dt * 16 + l15] =
                f2b(O[dt][r] * inv[r]);
        }
}

// ---------------------------------------------------------------------------
// Kernel 3: output projection, bf16 MFMA GEMM, BK=64 (halved barriers).
// ---------------------------------------------------------------------------
__global__ __launch_bounds__(256) void outproj_kernel(
    const ushort* __restrict__ ctx, const ushort* __restrict__ wt,
    float* __restrict__ out)
{
    __shared__ ushort Asm[128 * 64];
    __shared__ ushort Bsm[128 * 64];

    const int tid  = threadIdx.x;
    const int wave = tid >> 6, lane = tid & 63;
    const int quad = lane >> 4, l15 = lane & 15;
    const int row0 = blockIdx.x * 128;
    const int col0 = blockIdx.y * 128;
    const int wr = wave >> 1, wc = wave & 1;

    const ushort* A  = ctx + (size_t)row0 * SDM;
    const ushort* Bw = wt + (size_t)4 * (SDM * SDM) + (size_t)col0 * SDM;

    f32x4 acc[4][4];
#pragma unroll
    for (int i = 0; i < 4; ++i)
#pragma unroll
        for (int j = 0; j < 4; ++j) acc[i][j] = (f32x4){0.f, 0.f, 0.f, 0.f};

    for (int k0 = 0; k0 < SDM; k0 += 64) {
#pragma unroll
        for (int j = 0; j < 4; ++j) {
            int t = j * 256 + tid;
            int r = t >> 3, kp = (t & 7) * 8;
            gll16(A  + (size_t)r * SDM + k0 + kp, (char*)Asm + t * 16);
            gll16(Bw + (size_t)r * SDM + k0 + kp, (char*)Bsm + t * 16);
        }
        __syncthreads();

#pragma unroll
        for (int kk = 0; kk < 2; ++kk) {
            bf16x8 af[4], bfr[4];
#pragma unroll
            for (int mt = 0; mt < 4; ++mt)
                af[mt] = *(const bf16x8*)&Asm[(wr * 64 + mt * 16 + l15) * 64 + kk * 32 + quad * 8];
#pragma unroll
            for (int nt = 0; nt < 4; ++nt)
                bfr[nt] = *(const bf16x8*)&Bsm[(wc * 64 + nt * 16 + l15) * 64 + kk * 32 + quad * 8];
#pragma unroll
            for (int mt = 0; mt < 4; ++mt)
#pragma unroll
                for (int nt = 0; nt < 4; ++nt)
                    acc[mt][nt] = MFMA16(af[mt], bfr[nt], acc[mt][nt]);
        }
        __syncthreads();
    }

#pragma unroll
    for (int mt = 0; mt < 4; ++mt)
#pragma unroll
        for (int nt = 0; nt < 4; ++nt) {
            const int R = row0 + wr * 64 + mt * 16 + quad * 4;
            const int C = col0 + wc * 64 + nt * 16 + l15;
#pragma unroll
            for (int r = 0; r < 4; ++r)
                out[(size_t)(R + r) * SDM + C] = acc[mt][nt][r];
        }
}

// ---------------------------------------------------------------------------
extern "C" void kernel_launch(void* const* d_in, const int* in_sizes, int n_in,
                              void* d_out, int out_size, void* d_ws, size_t ws_size,
                              hipStream_t stream)
{
    const float* query  = (const float*)d_in[0];
    const float* key    = (const float*)d_in[1];
    const float* value  = (const float*)d_in[2];
    const float* pos    = (const float*)d_in[3];
    const float* qw     = (const float*)d_in[4];
    const float* kw     = (const float*)d_in[5];
    const float* vw     = (const float*)d_in[6];
    const float* pw     = (const float*)d_in[7];
    const float* projw  = (const float*)d_in[8];
    const float* bias_u = (const float*)d_in[9];
    const float* bias_v = (const float*)d_in[10];

    char* w = (char*)d_ws;
    const size_t MB = 1024 * 1024;
    ushort* xbf = (ushort*)w;                 // 32 MB (dead after projmm)
    ushort* quo = (ushort*)(w + 32 * MB);
    ushort* qvo = (ushort*)(w + 40 * MB);
    ushort* ko  = (ushort*)(w + 48 * MB);
    ushort* po  = (ushort*)(w + 56 * MB);
    ushort* vto = (ushort*)(w + 64 * MB);     // chunk-tiled [bh][mc][d][64]
    ushort* wt  = (ushort*)(w + 72 * MB);     // 2.5 MB
    ushort* ctx = (ushort*)w;                 // aliases dead xbf

    dim3 gcx(2048, 4);
    convert_x_kernel<<<gcx, 256, 0, stream>>>(query, key, value, pos, xbf);
    dim3 gcw(1024, 5);
    convert_w_kernel<<<gcw, 256, 0, stream>>>(qw, kw, vw, pw, projw, wt);

    dim3 g1(64, 4, 4);
    projmm_kernel<<<g1, 256, 0, stream>>>(xbf, wt, bias_u, bias_v,
                                          quo, qvo, ko, po, vto);

    attn_kernel<<<dim3(1024), 256, 0, stream>>>(quo, qvo, ko, po, vto, ctx);

    dim3 g3(64, 4);
    outproj_kernel<<<g3, 256, 0, stream>>>(ctx, wt, (float*)d_out);
}